// Round 6
// baseline (853.488 us; speedup 1.0000x reference)
//
#include <hip/hip_runtime.h>
#include <hip/hip_fp16.h>
#include <math.h>

#define NF 32
#define BCAP 2560            // records per bin; mean ~2046, +11 sigma headroom

__device__ __forceinline__ void atomic_pk_add_f16(unsigned int* addr, unsigned int val) {
    asm volatile("global_atomic_pk_add_f16 %0, %1, off" :: "v"(addr), "v"(val) : "memory");
}

// ---- kernel 1: out-degree by src (for norm) --------------------------------
__global__ void count_kernel(const int* __restrict__ src, int* __restrict__ cnt, int E) {
    int e = blockIdx.x * blockDim.x + threadIdx.x;
    if (e < E) atomicAdd(&cnt[src[e]], 1);
}

// ---- kernel 2: dis = deg>0 ? rsqrt(deg) : 0 ; xs = f16x2(dis * x) ----------
__global__ void prescale_kernel(const float* __restrict__ x, const int* __restrict__ cnt,
                                float* __restrict__ dis, unsigned int* __restrict__ xs,
                                int N) {
    int t = blockIdx.x * blockDim.x + threadIdx.x;
    int n = t >> 4;
    int f2 = t & 15;
    if (n >= N) return;
    int d = cnt[n];
    float di = (d > 0) ? rsqrtf((float)d) : 0.0f;
    float2 xv = *(const float2*)(x + (size_t)n * NF + f2 * 2);
    unsigned short lo = __half_as_ushort(__float2half(di * xv.x));
    unsigned short hi = __half_as_ushort(__float2half(di * xv.y));
    xs[n * 16 + f2] = ((unsigned int)hi << 16) | lo;
    if (f2 == 0) dis[n] = di;
}

// ---- kernel 3a: bin fill — append (src<<7)|(dst&127) to bin dst>>7 ---------
__global__ void binfill_kernel(const int* __restrict__ src, const int* __restrict__ dst,
                               int* __restrict__ bin_cnt, unsigned int* __restrict__ bin_buf,
                               const unsigned int* __restrict__ xs,
                               unsigned int* __restrict__ acc, int E) {
    int e = blockIdx.x * blockDim.x + threadIdx.x;
    if (e >= E) return;
    int s = src[e];
    int d = dst[e];
    int bin = d >> 7;
    int pos = atomicAdd(&bin_cnt[bin], 1);
    if (pos < BCAP) {
        bin_buf[(size_t)bin * BCAP + pos] = ((unsigned int)s << 7) | (unsigned int)(d & 127);
    } else {
        // deterministic-overflow fallback: direct packed-f16 atomics (correct regardless)
        for (int f2 = 0; f2 < 16; ++f2)
            atomic_pk_add_f16(&acc[(size_t)d * 16 + f2], xs[(size_t)s * 16 + f2]);
    }
}

// ---- kernel 3b: per-bin LDS f32 accumulation, then merge into acc ----------
// one block per bin (128 nodes); 16 record-groups x 16 feature-pairs
__global__ __launch_bounds__(256) void binred_kernel(
    const unsigned int* __restrict__ xs, const unsigned int* __restrict__ bin_buf,
    const int* __restrict__ bin_cnt, unsigned int* __restrict__ acc, int N) {
    __shared__ float sacc[128 * 33];   // stride 33 to spread LDS banks
    int b = blockIdx.x;
    int t = threadIdx.x;
    for (int i = t; i < 128 * 33; i += 256) sacc[i] = 0.0f;
    __syncthreads();

    int cnt = bin_cnt[b];
    if (cnt > BCAP) cnt = BCAP;
    int f2 = t & 15;
    int rg = t >> 4;                   // record group 0..15
    const unsigned int* bb = bin_buf + (size_t)b * BCAP;

    for (int r = rg; r < cnt; r += 16) {
        unsigned int rec = bb[r];
        int dl = (int)(rec & 127u);
        unsigned int s = rec >> 7;
        unsigned int v = xs[(size_t)s * 16 + f2];
        __half2 h = *(__half2*)&v;
        atomicAdd(&sacc[dl * 33 + f2 * 2 + 0], __half2float(h.x));
        atomicAdd(&sacc[dl * 33 + f2 * 2 + 1], __half2float(h.y));
    }
    __syncthreads();

    int node0 = b * 128;
    for (int i = t; i < 128 * 16; i += 256) {
        int dl = i >> 4;
        int f  = i & 15;
        int node = node0 + dl;
        if (node >= N) continue;
        float lo = sacc[dl * 33 + f * 2 + 0];
        float hi = sacc[dl * 33 + f * 2 + 1];
        if (lo != 0.0f || hi != 0.0f) {
            unsigned short l = __half_as_ushort(__float2half(lo));
            unsigned short h = __half_as_ushort(__float2half(hi));
            atomic_pk_add_f16(&acc[(size_t)node * 16 + f], ((unsigned int)h << 16) | l);
        }
    }
}

// ---- kernel 4: gates + readout ---------------------------------------------
__global__ __launch_bounds__(256) void gate_kernel(
    const float* __restrict__ x, const unsigned short* __restrict__ acc16,
    const float* __restrict__ dis,
    const float* __restrict__ Wxz0, const float* __restrict__ Wxz1,
    const float* __restrict__ bxz,  const float* __restrict__ bhz,
    const float* __restrict__ Wxh0, const float* __restrict__ Wxh1,
    const float* __restrict__ bxh,  const float* __restrict__ bhh,
    const float* __restrict__ Wl,   const float* __restrict__ bl,
    float* __restrict__ out, int N)
{
    __shared__ float sWz0[NF * NF], sWz1[NF * NF], sWh0[NF * NF], sWh1[NF * NF];
    __shared__ float sbz[NF], sbh[NF], sWl[NF];
    __shared__ float sx[8][NF + 1], st[8][NF + 1];

    int t = threadIdx.x;
    for (int i = t; i < NF * NF; i += 256) {
        sWz0[i] = Wxz0[i];
        sWz1[i] = Wxz1[i];
        sWh0[i] = Wxh0[i];
        sWh1[i] = Wxh1[i];
    }
    if (t < NF) {
        sbz[t] = bxz[t] + bhz[t];
        sbh[t] = bxh[t] + bhh[t];
        sWl[t] = Wl[t];
    }

    int nl = t >> 5;
    int f  = t & 31;
    int node = blockIdx.x * 8 + nl;

    if (node < N) {
        sx[nl][f] = x[(size_t)node * NF + f];
        float dn = dis[node];
        float av = __half2float(__ushort_as_half(acc16[(size_t)node * NF + f]));
        st[nl][f] = -dn * av;   // tx1 = -dis[dst] * sum(dis[src] * x[src])
    }
    __syncthreads();
    if (node >= N) return;

    float az = sbz[f];
    float ah = sbh[f];
    #pragma unroll
    for (int k = 0; k < NF; ++k) {
        float xv = sx[nl][k];
        float tv = st[nl][k];
        az += xv * sWz0[k * NF + f] + tv * sWz1[k * NF + f];
        ah += xv * sWh0[k * NF + f] + tv * sWh1[k * NF + f];
    }

    float z  = 1.0f / (1.0f + expf(-az));
    float ht = tanhf(ah);
    float h  = (1.0f - z) * ht;
    float c  = fmaxf(h, 0.0f) * sWl[f];

    #pragma unroll
    for (int m = 16; m >= 1; m >>= 1) c += __shfl_xor(c, m, 64);

    if (f == 0) out[node] = c + bl[0];
}

extern "C" void kernel_launch(void* const* d_in, const int* in_sizes, int n_in,
                              void* d_out, int out_size, void* d_ws, size_t ws_size,
                              hipStream_t stream) {
    const float* x    = (const float*)d_in[0];
    const int*   edge = (const int*)d_in[1];   // [2, E]: src row then dst row
    const float* Wxz0 = (const float*)d_in[2];
    const float* Wxz1 = (const float*)d_in[3];
    const float* bxz  = (const float*)d_in[4];
    const float* bhz  = (const float*)d_in[7];
    const float* Wxh0 = (const float*)d_in[14];
    const float* Wxh1 = (const float*)d_in[15];
    const float* bxh  = (const float*)d_in[16];
    const float* bhh  = (const float*)d_in[19];
    const float* Wl   = (const float*)d_in[20];
    const float* bl   = (const float*)d_in[21];
    float* out = (float*)d_out;

    int N = in_sizes[0] / NF;
    int E = in_sizes[1] / 2;
    const int* src = edge;
    const int* dst = edge + E;

    int nbin = (N + 127) >> 7;

    // ws (4B elems): [zeroed: cnt[N] | acc[16N] | bin_cnt[nbin_pad]] | dis[N] | xs[16N] | bin_buf[nbin*BCAP]
    int nbin_pad = (nbin + 255) & ~255;
    int*          cnt     = (int*)d_ws;
    unsigned int* acc     = (unsigned int*)(cnt + N);
    int*          bin_cnt = (int*)(acc + (size_t)N * 16);
    float*        dis     = (float*)(bin_cnt + nbin_pad);
    unsigned int* xs      = (unsigned int*)(dis + N);
    unsigned int* bin_buf = xs + (size_t)N * 16;

    hipMemsetAsync(d_ws, 0, (size_t)(17 * (size_t)N + nbin_pad) * sizeof(int), stream);

    int eb = (E + 255) / 256;
    count_kernel<<<eb, 256, 0, stream>>>(src, cnt, E);

    int pt = N * 16;
    prescale_kernel<<<(pt + 255) / 256, 256, 0, stream>>>(x, cnt, dis, xs, N);

    binfill_kernel<<<eb, 256, 0, stream>>>(src, dst, bin_cnt, bin_buf, xs, acc, E);
    binred_kernel<<<nbin, 256, 0, stream>>>(xs, bin_buf, bin_cnt, acc, N);

    gate_kernel<<<(N + 7) / 8, 256, 0, stream>>>(
        x, (const unsigned short*)acc, dis,
        Wxz0, Wxz1, bxz, bhz, Wxh0, Wxh1, bxh, bhh, Wl, bl, out, N);
}

// Round 7
// 219.517 us; speedup vs baseline: 3.8880x; 3.8880x over previous
//
#include <hip/hip_runtime.h>
#include <hip/hip_fp16.h>
#include <math.h>

#define NF 32

__device__ __forceinline__ void atomic_pk_add_f16(unsigned int* addr, unsigned int val) {
    asm volatile("global_atomic_pk_add_f16 %0, %1, off" :: "v"(addr), "v"(val) : "memory");
}

// ---- kernel 1: out-degree by src (for norm) --------------------------------
__global__ void count_kernel(const int* __restrict__ src, int* __restrict__ cnt, int E) {
    int e = blockIdx.x * blockDim.x + threadIdx.x;
    if (e < E) atomicAdd(&cnt[src[e]], 1);
}

// ---- kernel 2: dis = deg>0 ? rsqrt(deg) : 0 ; xs = f16x2(dis*x); acc = 0 ---
__global__ void prescale_kernel(const float* __restrict__ x, const int* __restrict__ cnt,
                                float* __restrict__ dis, unsigned int* __restrict__ xs,
                                unsigned int* __restrict__ acc, int N) {
    int t = blockIdx.x * blockDim.x + threadIdx.x;
    int n = t >> 4;
    int f2 = t & 15;
    if (n >= N) return;
    acc[t] = 0u;
    int d = cnt[n];
    float di = (d > 0) ? rsqrtf((float)d) : 0.0f;
    float2 xv = *(const float2*)(x + (size_t)n * NF + f2 * 2);
    unsigned short lo = __half_as_ushort(__float2half(di * xv.x));
    unsigned short hi = __half_as_ushort(__float2half(di * xv.y));
    xs[n * 16 + f2] = ((unsigned int)hi << 16) | lo;
    if (f2 == 0) dis[n] = di;
}

// ---- kernel 3: scatter acc[dst] += xs[src]  (packed f16 atomics) -----------
__global__ void scatter_kernel(const int* __restrict__ src, const int* __restrict__ dst,
                               const unsigned int* __restrict__ xs,
                               unsigned int* __restrict__ acc, int E) {
    int t = blockIdx.x * blockDim.x + threadIdx.x;
    int e = t >> 4;
    int f2 = t & 15;
    if (e >= E) return;
    int s = src[e];
    int d = dst[e];
    unsigned int v = xs[s * 16 + f2];
    atomic_pk_add_f16(&acc[d * 16 + f2], v);
}

// ---- kernel 4: gates + readout (grid-stride; weights staged once/block) ----
#define GATE_BLOCKS 2048
__global__ __launch_bounds__(256) void gate_kernel(
    const float* __restrict__ x, const unsigned short* __restrict__ acc16,
    const float* __restrict__ dis,
    const float* __restrict__ Wxz0, const float* __restrict__ Wxz1,
    const float* __restrict__ bxz,  const float* __restrict__ bhz,
    const float* __restrict__ Wxh0, const float* __restrict__ Wxh1,
    const float* __restrict__ bxh,  const float* __restrict__ bhh,
    const float* __restrict__ Wl,   const float* __restrict__ bl,
    float* __restrict__ out, int N)
{
    __shared__ float sWz0[NF * NF], sWz1[NF * NF], sWh0[NF * NF], sWh1[NF * NF];
    __shared__ float sbz[NF], sbh[NF], sWl[NF];
    __shared__ float sx[8][NF + 1], st[8][NF + 1];

    int t = threadIdx.x;
    for (int i = t; i < NF * NF; i += 256) {
        sWz0[i] = Wxz0[i];
        sWz1[i] = Wxz1[i];
        sWh0[i] = Wxh0[i];
        sWh1[i] = Wxh1[i];
    }
    if (t < NF) {
        sbz[t] = bxz[t] + bhz[t];
        sbh[t] = bxh[t] + bhh[t];
        sWl[t] = Wl[t];
    }

    int nl = t >> 5;
    int f  = t & 31;
    float blv = bl[0];
    int step = gridDim.x * 8;

    for (int node0 = blockIdx.x * 8; node0 < N; node0 += step) {
        int node = node0 + nl;
        __syncthreads();            // protect st/sx from previous iteration's readers
        if (node < N) {
            sx[nl][f] = x[(size_t)node * NF + f];
            float dn = dis[node];
            float av = __half2float(__ushort_as_half(acc16[(size_t)node * NF + f]));
            st[nl][f] = -dn * av;   // tx1 = -dis[dst] * sum(dis[src]*x[src])
        }
        __syncthreads();
        if (node >= N) continue;

        float az = sbz[f];
        float ah = sbh[f];
        #pragma unroll
        for (int k = 0; k < NF; ++k) {
            float xv = sx[nl][k];
            float tv = st[nl][k];
            az += xv * sWz0[k * NF + f] + tv * sWz1[k * NF + f];
            ah += xv * sWh0[k * NF + f] + tv * sWh1[k * NF + f];
        }

        float z  = 1.0f / (1.0f + expf(-az));
        float ht = tanhf(ah);
        float h  = (1.0f - z) * ht;
        float c  = fmaxf(h, 0.0f) * sWl[f];

        #pragma unroll
        for (int m = 16; m >= 1; m >>= 1) c += __shfl_xor(c, m, 64);

        if (f == 0) out[node] = c + blv;
    }
}

extern "C" void kernel_launch(void* const* d_in, const int* in_sizes, int n_in,
                              void* d_out, int out_size, void* d_ws, size_t ws_size,
                              hipStream_t stream) {
    const float* x    = (const float*)d_in[0];
    const int*   edge = (const int*)d_in[1];   // [2, E]: src row then dst row
    const float* Wxz0 = (const float*)d_in[2];
    const float* Wxz1 = (const float*)d_in[3];
    const float* bxz  = (const float*)d_in[4];
    const float* bhz  = (const float*)d_in[7];
    const float* Wxh0 = (const float*)d_in[14];
    const float* Wxh1 = (const float*)d_in[15];
    const float* bxh  = (const float*)d_in[16];
    const float* bhh  = (const float*)d_in[19];
    const float* Wl   = (const float*)d_in[20];
    const float* bl   = (const float*)d_in[21];
    float* out = (float*)d_out;

    int N = in_sizes[0] / NF;
    int E = in_sizes[1] / 2;
    const int* src = edge;
    const int* dst = edge + E;

    // ws (4B elems): cnt[N] | acc[16N] | dis[N] | xs[16N]
    int*          cnt = (int*)d_ws;
    unsigned int* acc = (unsigned int*)(cnt + N);
    float*        dis = (float*)(acc + (size_t)N * 16);
    unsigned int* xs  = (unsigned int*)(dis + N);

    hipMemsetAsync(cnt, 0, (size_t)N * sizeof(int), stream);

    count_kernel<<<(E + 255) / 256, 256, 0, stream>>>(src, cnt, E);

    int pt = N * 16;
    prescale_kernel<<<(pt + 255) / 256, 256, 0, stream>>>(x, cnt, dis, xs, acc, N);

    long long stt = (long long)E * 16;
    scatter_kernel<<<(int)((stt + 255) / 256), 256, 0, stream>>>(src, dst, xs, acc, E);

    int gate_blocks = (N + 7) / 8;
    if (gate_blocks > GATE_BLOCKS) gate_blocks = GATE_BLOCKS;
    gate_kernel<<<gate_blocks, 256, 0, stream>>>(
        x, (const unsigned short*)acc, dis,
        Wxz0, Wxz1, bxz, bhz, Wxh0, Wxh1, bxh, bhh, Wl, bl, out, N);
}